// Round 2
// baseline (401.777 us; speedup 1.0000x reference)
//
#include <hip/hip_runtime.h>

#define BS   64
#define NQ   3000
#define NC   256
#define FH   100
#define FW   100
#define TOPK 1500

// ---------------- Kernel A: scores[b,q] = max_c class[b,q,c] ----------------
// One row (64 float4) per wave-iteration; 4 rows per wave for 4 outstanding
// loads. Lane l reads float4 l of each row (1 KB coalesced per instruction).
// Memory-bound at ~31 us floor (196.6 MB @ 6.3 TB/s) — near roofline.
// Also zeroes the per-batch completion counters used by raster's fused emit
// (workspace is re-poisoned every iteration, so this must happen every run).
__global__ __launch_bounds__(256) void scores_kernel(const float4* __restrict__ cls,
                                                     float* __restrict__ scores,
                                                     int* __restrict__ counters) {
    const int tid  = threadIdx.x;
    const int lane = tid & 63;
    const int wave = tid >> 6;
    const int row0 = blockIdx.x * 16 + wave * 4;  // 16 rows per block, grid exact
    if (blockIdx.x == 0 && tid < BS) counters[tid] = 0;
    const float4* p = cls + (size_t)row0 * (NC / 4) + lane;
    float4 a = p[0], b = p[64], c = p[128], d = p[192];
    float m0 = fmaxf(fmaxf(a.x, a.y), fmaxf(a.z, a.w));
    float m1 = fmaxf(fmaxf(b.x, b.y), fmaxf(b.z, b.w));
    float m2 = fmaxf(fmaxf(c.x, c.y), fmaxf(c.z, c.w));
    float m3 = fmaxf(fmaxf(d.x, d.y), fmaxf(d.z, d.w));
#pragma unroll
    for (int off = 32; off > 0; off >>= 1) {
        m0 = fmaxf(m0, __shfl_xor(m0, off, 64));
        m1 = fmaxf(m1, __shfl_xor(m1, off, 64));
        m2 = fmaxf(m2, __shfl_xor(m2, off, 64));
        m3 = fmaxf(m3, __shfl_xor(m3, off, 64));
    }
    if (lane < 4) {
        float m = (lane == 0) ? m0 : (lane == 1) ? m1 : (lane == 2) ? m2 : m3;
        scores[row0 + lane] = m;
    }
}

// ---------------- Kernel B: select + raster + (last block) emit --------------
// Grid (NSPLIT, BS) = 512 blocks. Every block redundantly computes the
// per-batch threshold (redundancy is free: blocks run in parallel on idle
// CUs) then rasterizes only its NQ/NSPLIT query slice into a private LDS
// bitmap. The last block to finish a batch (device-scope atomic counter)
// ORs the NSPLIT partial planes and emits the float mask fused with padding.
#define NSPLIT 8
#define NTM    512  // 8 waves
#define QSLICE ((NQ + NSPLIT - 1) / NSPLIT)

__global__ __launch_bounds__(NTM) void raster_kernel(const float4* __restrict__ coord,
                                                     const int* __restrict__ vfs,
                                                     const float* __restrict__ scores,
                                                     unsigned* __restrict__ pcov,
                                                     int* __restrict__ counters,
                                                     float* __restrict__ out) {
    __shared__ __align__(16) unsigned su[NQ];  // score bits (positive floats: uint order == float order)
    __shared__ int      hist[8][256];  // per-wave histograms
    __shared__ unsigned cov[FH * 4];   // 100 rows x 128-bit coverage (this slice only)
    __shared__ int      eqlist[NQ];    // 24-bit-prefix candidates from pass 3
    __shared__ int      wave_sum[4];
    __shared__ int      s_selbin, s_K, s_c24, s_qcut, s_last;

    const int part = blockIdx.x;       // slice within batch
    const int b    = blockIdx.y;       // batch
    const int tid  = threadIdx.x;
    const int wid  = tid >> 6;

    // vectorized score load: NQ*4B = 12000B per batch, 16B-aligned, 750 uint4
    {
        const uint4* sp = (const uint4*)(scores + b * NQ);
        uint4* sd = (uint4*)su;
        for (int i = tid; i < NQ / 4; i += NTM) sd[i] = sp[i];
    }
    for (int i = tid; i < FH * 4; i += NTM) cov[i] = 0u;
    if (tid == 0) s_c24 = 0;

    // ---- byte-wise radix descent with wave-aggregated histogram ----
    // Scores are maxes of 256 uniforms -> nearly all share the top byte(s);
    // naive per-lane atomicAdd serializes ~375 same-address adds per wave.
    // Ballot-aggregate: if all active lanes in a wave hit one bin, a single
    // leader adds popcount. Tie candidates (24-bit prefix match) are
    // collected during pass 3, eliminating a separate full-NQ pass.
    unsigned prefix = 0, pmask = 0;
    int K = TOPK;
#pragma unroll
    for (int p = 0; p < 4; ++p) {
        const int shift = 24 - 8 * p;
        for (int i = tid; i < 8 * 256; i += NTM) ((int*)hist)[i] = 0;
        __syncthreads();
        for (int q = tid; q < NQ; q += NTM) {
            unsigned u   = su[q];
            bool     pr  = ((u & pmask) == prefix);
            unsigned bin = (u >> shift) & 0xFF;
            if (p == 3 && pr) eqlist[atomicAdd(&s_c24, 1)] = q;
            unsigned long long act = __ballot(pr);
            if (act) {  // wave-uniform branch
                int leader = __ffsll((long long)act) - 1;
                unsigned fb = (unsigned)__shfl((int)bin, leader, 64);
                unsigned long long same = __ballot(pr && bin == fb);
                if (same == act) {
                    if ((tid & 63) == leader) atomicAdd(&hist[wid][fb], (int)__popcll(act));
                } else if (pr) {
                    atomicAdd(&hist[wid][bin], 1);
                }
            }
        }
        __syncthreads();
        // first 256 threads: suffix scan over bins (reversed index = prefix scan)
        int x = 0, hx = 0, bin = 0;
        if (tid < 256) {
            bin = 255 - tid;
            hx = hist[0][bin] + hist[1][bin] + hist[2][bin] + hist[3][bin] +
                 hist[4][bin] + hist[5][bin] + hist[6][bin] + hist[7][bin];
            x = hx;
#pragma unroll
            for (int off = 1; off < 64; off <<= 1) {
                int y = __shfl_up(x, off, 64);
                if ((tid & 63) >= off) x += y;
            }
            if ((tid & 63) == 63) wave_sum[tid >> 6] = x;
        }
        __syncthreads();
        if (tid < 256) {
            int w = tid >> 6;
            for (int j = 0; j < w; ++j) x += wave_sum[j];
            int ge_incl = x;          // count of prefix-matching su with byte >= bin
            int ge_excl = x - hx;     // count with byte > bin
            if (ge_incl >= K && ge_excl < K) {
                s_selbin = bin;
                s_K      = K - ge_excl;
            }
        }
        __syncthreads();
        prefix |= ((unsigned)s_selbin) << shift;
        pmask  |= (0xFFu << shift);
        K = s_K;
        __syncthreads();
    }
    const unsigned v      = prefix;  // exact bits of TOPK-th largest
    const int      e_take = K;       // how many su==v to take (smallest indices)

    // ---- tie cutoff from pass-3 candidates: tie q selected iff q < qcut ----
    const int C24 = s_c24;           // candidates matching 24-bit prefix (tiny)
    for (int i = tid; i < C24; i += NTM) {
        int q = eqlist[i];
        if (su[q] == v) {
            int r = 0;
            for (int j = 0; j < C24; ++j) {
                int qj = eqlist[j];
                r += (su[qj] == v && qj < q) ? 1 : 0;
            }
            if (r == e_take - 1) s_qcut = q + 1;  // unique writer
        }
    }
    __syncthreads();
    const int qcut = s_qcut;

    const float s0 = (float)vfs[2 * b];      // reference scales x by vfs[:,0]
    const float s1 = (float)vfs[2 * b + 1];  // and y by vfs[:,1] (quirk replicated)

    // ---- raster own slice only: ~QSLICE/NSPLIT boxes, <=1 per thread ----
    const int q0 = part * QSLICE;
    const int q1 = (q0 + QSLICE < NQ) ? (q0 + QSLICE) : NQ;
    for (int q = q0 + tid; q < q1; q += NTM) {
        unsigned u = su[q];
        if (u > v || (u == v && q < qcut)) {
            float4 c4 = coord[(size_t)b * NQ + q];
            float x1 = c4.x - 0.5f * c4.z, y1 = c4.y - 0.5f * c4.w;
            float x2 = c4.x + 0.5f * c4.z, y2 = c4.y + 0.5f * c4.w;
            int lx = (int)floorf(x1 * s0), ly = (int)floorf(y1 * s1);
            int rx = (int)floorf(x2 * s0), ry = (int)floorf(y2 * s1);
            int h0 = ly > 0 ? ly : 0, h1 = ry < FH ? ry : FH;
            int w0 = lx > 0 ? lx : 0, w1 = rx < FW ? rx : FW;
            if (h0 < h1 && w0 < w1) {
                unsigned m[4];
#pragma unroll
                for (int j = 0; j < 4; ++j) {
                    int lo = w0 - 32 * j; lo = lo < 0 ? 0 : lo;
                    int hi = w1 - 32 * j; hi = hi > 32 ? 32 : hi;
                    unsigned mm = 0u;
                    if (hi > lo) {
                        unsigned top = (hi >= 32) ? 0xFFFFFFFFu : ((1u << hi) - 1u);
                        unsigned bot = (lo <= 0) ? 0u : ((1u << lo) - 1u);
                        mm = top & ~bot;
                    }
                    m[j] = mm;
                }
                for (int h = h0; h < h1; ++h) {
#pragma unroll
                    for (int j = 0; j < 4; ++j)
                        if (m[j]) atomicOr(&cov[h * 4 + j], m[j]);
                }
            }
        }
    }
    __syncthreads();

    // ---- dump partial plane, then last block per batch emits -------------
    {
        unsigned* dst = pcov + (size_t)(b * NSPLIT + part) * (FH * 4);
        for (int i = tid; i < FH * 4; i += NTM) dst[i] = cov[i];
    }
    __threadfence();       // release: my plane visible at agent scope
    __syncthreads();       // all threads' stores+fences done before the RMW
    if (tid == 0) {
        int prev = __hip_atomic_fetch_add(&counters[b], 1, __ATOMIC_ACQ_REL,
                                          __HIP_MEMORY_SCOPE_AGENT);
        s_last = (prev == NSPLIT - 1) ? 1 : 0;
    }
    __syncthreads();
    if (s_last) {
        __threadfence();   // acquire: invalidate stale L1/L2 before reading peers
        const int iv0 = vfs[2 * b], iv1 = vfs[2 * b + 1];
        const unsigned* pb = pcov + (size_t)b * NSPLIT * (FH * 4);
        for (int idx = tid; idx < FH * FW; idx += NTM) {
            int h = idx / FW;
            int w = idx - h * FW;
            const unsigned* pp = pb + h * 4 + (w >> 5);
            unsigned acc = 0u;
#pragma unroll
            for (int s = 0; s < NSPLIT; ++s) acc |= pp[s * (FH * 4)];
            bool covered = (acc >> (w & 31)) & 1u;
            bool pad = (h >= iv0) || (w >= iv1);
            out[(size_t)b * (FH * FW) + idx] = (covered && !pad) ? 0.0f : -1e20f;
        }
    }
}

extern "C" void kernel_launch(void* const* d_in, const int* in_sizes, int n_in,
                              void* d_out, int out_size, void* d_ws, size_t ws_size,
                              hipStream_t stream) {
    const float4* coord = (const float4*)d_in[0];  // (BS, NQ, 4) f32
    const float*  cls   = (const float*)d_in[1];   // (BS, NQ, NC) f32
    const int*    vfs   = (const int*)d_in[2];     // (BS, 2) i32
    // d_in[3] (padding_mask) ignored — recomputed from vfs.
    float*    scores   = (float*)d_ws;                               // 768000 B
    unsigned* pcov     = (unsigned*)((char*)d_ws + (size_t)BS * NQ * sizeof(float));
                                                                     // 819200 B
    int*      counters = (int*)((char*)d_ws + (size_t)BS * NQ * sizeof(float)
                                            + (size_t)BS * NSPLIT * FH * 4 * sizeof(unsigned));
    float* out = (float*)d_out;

    const int rows = BS * NQ;  // 192000
    scores_kernel<<<rows / 16, 256, 0, stream>>>((const float4*)cls, scores, counters);
    raster_kernel<<<dim3(NSPLIT, BS), NTM, 0, stream>>>(coord, vfs, scores, pcov, counters, out);
}

// Round 3
// 323.631 us; speedup vs baseline: 1.2415x; 1.2415x over previous
//
#include <hip/hip_runtime.h>

#define BS   64
#define NQ   3000
#define NC   256
#define FH   100
#define FW   100
#define TOPK 1500

// ---------------- Kernel A: scores[b,q] = max_c class[b,q,c] ----------------
// One row (64 float4) per wave-iteration; 4 rows per wave for 4 outstanding
// loads. Lane l reads float4 l of each row (1 KB coalesced per instruction).
// Memory-bound at ~31 us floor (196.6 MB @ 6.3 TB/s) — at roofline.
__global__ __launch_bounds__(256) void scores_kernel(const float4* __restrict__ cls,
                                                     float* __restrict__ scores) {
    const int tid  = threadIdx.x;
    const int lane = tid & 63;
    const int wave = tid >> 6;
    const int row0 = blockIdx.x * 16 + wave * 4;  // 16 rows per block, grid exact
    const float4* p = cls + (size_t)row0 * (NC / 4) + lane;
    float4 a = p[0], b = p[64], c = p[128], d = p[192];
    float m0 = fmaxf(fmaxf(a.x, a.y), fmaxf(a.z, a.w));
    float m1 = fmaxf(fmaxf(b.x, b.y), fmaxf(b.z, b.w));
    float m2 = fmaxf(fmaxf(c.x, c.y), fmaxf(c.z, c.w));
    float m3 = fmaxf(fmaxf(d.x, d.y), fmaxf(d.z, d.w));
#pragma unroll
    for (int off = 32; off > 0; off >>= 1) {
        m0 = fmaxf(m0, __shfl_xor(m0, off, 64));
        m1 = fmaxf(m1, __shfl_xor(m1, off, 64));
        m2 = fmaxf(m2, __shfl_xor(m2, off, 64));
        m3 = fmaxf(m3, __shfl_xor(m3, off, 64));
    }
    if (lane < 4) {
        float m = (lane == 0) ? m0 : (lane == 1) ? m1 : (lane == 2) ? m2 : m3;
        scores[row0 + lane] = m;
    }
}

// ---------------- Kernel B: per-(batch,slice) select + gather-raster --------
// Grid (NSPLIT, BS) = 512 blocks, all co-resident. Every block redundantly
// computes the per-batch threshold (radix descent; redundancy is parallel =
// free) and the scalar tie cutoff qcut, then compacts its slice's selected
// boxes into a packed LDS list and GATHER-rasters: one thread per coverage
// word loops the box list (LDS broadcast reads, conflict-free), accumulates
// in a register, writes straight to the partial plane. No LDS atomicOr —
// Round-2 counters showed 1.39M conflict-cycles from scatter atomicOr.
// NO device-scope fences: the raster->emit kernel boundary is the coherence
// point (Round-2 fused-emit fences cost 170us of L2 writeback/invalidate).
#define NSPLIT 8
#define NTM    512  // 8 waves
#define QSLICE ((NQ + NSPLIT - 1) / NSPLIT)  // 375

__global__ __launch_bounds__(NTM) void raster_kernel(const float4* __restrict__ coord,
                                                     const int* __restrict__ vfs,
                                                     const float* __restrict__ scores,
                                                     unsigned* __restrict__ pcov) {
    __shared__ __align__(16) unsigned su[NQ];  // score bits (positive: uint order == float order)
    __shared__ int      hist[8][256];   // per-wave histograms
    __shared__ int      eqlist[NQ];     // ties at v (worst case all)
    __shared__ unsigned boxlist[QSLICE];// packed clipped rects of this slice
    __shared__ int      wave_sum[4];
    __shared__ int      s_selbin, s_K, s_ecnt, s_qcut, s_nbox;

    const int part = blockIdx.x;       // slice within batch
    const int b    = blockIdx.y;       // batch
    const int tid  = threadIdx.x;
    const int wid  = tid >> 6;

    // vectorized score load: NQ*4B = 12000B, 16B-aligned, 750 uint4
    {
        const uint4* sp = (const uint4*)(scores + b * NQ);
        uint4* sd = (uint4*)su;
        for (int i = tid; i < NQ / 4; i += NTM) sd[i] = sp[i];
    }
    if (tid == 0) { s_ecnt = 0; s_nbox = 0; }

    // ---- byte-wise radix descent with parallel suffix-scan bin select ----
    unsigned prefix = 0, pmask = 0;
    int K = TOPK;
#pragma unroll
    for (int p = 0; p < 4; ++p) {
        const int shift = 24 - 8 * p;
        for (int i = tid; i < 8 * 256; i += NTM) ((int*)hist)[i] = 0;
        __syncthreads();
        for (int q = tid; q < NQ; q += NTM) {
            unsigned u = su[q];
            if ((u & pmask) == prefix)
                atomicAdd(&hist[wid][(u >> shift) & 0xFF], 1);
        }
        __syncthreads();
        // first 256 threads: suffix scan over bins (reversed index = prefix scan)
        int x = 0, hx = 0, bin = 0;
        if (tid < 256) {
            bin = 255 - tid;
            hx = hist[0][bin] + hist[1][bin] + hist[2][bin] + hist[3][bin] +
                 hist[4][bin] + hist[5][bin] + hist[6][bin] + hist[7][bin];
            x = hx;
#pragma unroll
            for (int off = 1; off < 64; off <<= 1) {
                int y = __shfl_up(x, off, 64);
                if ((tid & 63) >= off) x += y;
            }
            if ((tid & 63) == 63) wave_sum[tid >> 6] = x;
        }
        __syncthreads();
        if (tid < 256) {
            int w = tid >> 6;
            for (int j = 0; j < w; ++j) x += wave_sum[j];
            int ge_incl = x;          // count of prefix-matching su with byte >= bin
            int ge_excl = x - hx;     // count with byte > bin
            if (ge_incl >= K && ge_excl < K) {
                s_selbin = bin;
                s_K      = K - ge_excl;
            }
        }
        __syncthreads();
        prefix |= ((unsigned)s_selbin) << shift;
        pmask  |= (0xFFu << shift);
        K = s_K;
        __syncthreads();
    }
    const unsigned v      = prefix;  // exact bits of TOPK-th largest
    const int      e_take = K;       // how many su==v to take (smallest indices)

    // ---- resolve tie cutoff: tie q selected iff q < qcut ----
    for (int q = tid; q < NQ; q += NTM)
        if (su[q] == v) { int i = atomicAdd(&s_ecnt, 1); eqlist[i] = q; }
    __syncthreads();
    const int E = s_ecnt;  // E >= e_take >= 1 by construction
    for (int i = tid; i < E; i += NTM) {
        int q = eqlist[i];
        int r = 0;
        for (int j = 0; j < E; ++j) r += (eqlist[j] < q) ? 1 : 0;
        if (r == e_take - 1) s_qcut = q + 1;  // unique writer (indices distinct)
    }
    __syncthreads();
    const int qcut = s_qcut;

    const float s0 = (float)vfs[2 * b];      // reference scales x by vfs[:,0]
    const float s1 = (float)vfs[2 * b + 1];  // and y by vfs[:,1] (quirk replicated)

    // ---- phase 1: compact this slice's selected boxes (clipped, packed) ----
    const int q0 = part * QSLICE;
    const int q1 = (q0 + QSLICE < NQ) ? (q0 + QSLICE) : NQ;
    for (int q = q0 + tid; q < q1; q += NTM) {
        unsigned u = su[q];
        if (u > v || (u == v && q < qcut)) {
            float4 c4 = coord[(size_t)b * NQ + q];
            float x1 = c4.x - 0.5f * c4.z, y1 = c4.y - 0.5f * c4.w;
            float x2 = c4.x + 0.5f * c4.z, y2 = c4.y + 0.5f * c4.w;
            int lx = (int)floorf(x1 * s0), ly = (int)floorf(y1 * s1);
            int rx = (int)floorf(x2 * s0), ry = (int)floorf(y2 * s1);
            int h0 = ly > 0 ? ly : 0, h1 = ry < FH ? ry : FH;
            int w0 = lx > 0 ? lx : 0, w1 = rx < FW ? rx : FW;
            if (h0 < h1 && w0 < w1) {
                unsigned pk = (unsigned)h0 | ((unsigned)h1 << 8) |
                              ((unsigned)w0 << 16) | ((unsigned)w1 << 24);
                boxlist[atomicAdd(&s_nbox, 1)] = pk;
            }
        }
    }
    __syncthreads();

    // ---- phase 2: gather-raster, one thread per coverage word -------------
    const int nbox = s_nbox;
    if (tid < FH * 4) {
        const int h = tid >> 2, j = tid & 3;
        unsigned acc = 0u;
        for (int i = 0; i < nbox; ++i) {
            unsigned pk = boxlist[i];   // same address all lanes: LDS broadcast
            int h0 = (int)(pk & 0xFF), h1 = (int)((pk >> 8) & 0xFF);
            int w0 = (int)((pk >> 16) & 0xFF), w1 = (int)((pk >> 24) & 0xFF);
            int lo = w0 - 32 * j; lo = lo < 0 ? 0 : lo;
            int hi = w1 - 32 * j; hi = hi > 32 ? 32 : hi;
            unsigned top = (hi >= 32) ? 0xFFFFFFFFu : ((1u << (hi > 0 ? hi : 0)) - 1u);
            unsigned bot = (lo <= 0) ? 0u : ((1u << lo) - 1u);
            unsigned mm  = (hi > lo) ? (top & ~bot) : 0u;
            unsigned act = (h >= h0 && h < h1) ? 0xFFFFFFFFu : 0u;  // branchless
            acc |= mm & act;
        }
        pcov[(size_t)(b * NSPLIT + part) * (FH * 4) + tid] = acc;
    }
}

// ---------------- Kernel C: OR partials + fuse padding -> mask --------------
__global__ __launch_bounds__(256) void emit_kernel(const unsigned* __restrict__ pcov,
                                                   const int* __restrict__ vfs,
                                                   float* __restrict__ out) {
    const int idx = blockIdx.x * 256 + threadIdx.x;  // grid exact: BS*FH*FW
    if (idx >= BS * FH * FW) return;
    const int b    = idx / (FH * FW);
    const int cell = idx - b * (FH * FW);
    const int h    = cell / FW;
    const int w    = cell - h * FW;
    const unsigned* p = pcov + (size_t)b * NSPLIT * (FH * 4) + h * 4 + (w >> 5);
    unsigned acc = 0u;
#pragma unroll
    for (int s = 0; s < NSPLIT; ++s) acc |= p[s * (FH * 4)];
    const bool covered = (acc >> (w & 31)) & 1u;
    const bool pad     = (h >= vfs[2 * b]) || (w >= vfs[2 * b + 1]);
    out[idx] = (covered && !pad) ? 0.0f : -1e20f;
}

extern "C" void kernel_launch(void* const* d_in, const int* in_sizes, int n_in,
                              void* d_out, int out_size, void* d_ws, size_t ws_size,
                              hipStream_t stream) {
    const float4* coord = (const float4*)d_in[0];  // (BS, NQ, 4) f32
    const float*  cls   = (const float*)d_in[1];   // (BS, NQ, NC) f32
    const int*    vfs   = (const int*)d_in[2];     // (BS, 2) i32
    // d_in[3] (padding_mask) ignored — recomputed from vfs.
    float*    scores = (float*)d_ws;                           // 768000 B
    unsigned* pcov   = (unsigned*)((char*)d_ws + (size_t)BS * NQ * sizeof(float));
                                                               // 819200 B
    float* out = (float*)d_out;

    const int rows = BS * NQ;  // 192000
    scores_kernel<<<rows / 16, 256, 0, stream>>>((const float4*)cls, scores);
    raster_kernel<<<dim3(NSPLIT, BS), NTM, 0, stream>>>(coord, vfs, scores, pcov);
    emit_kernel<<<(BS * FH * FW) / 256, 256, 0, stream>>>(pcov, vfs, out);
}

// Round 4
// 309.024 us; speedup vs baseline: 1.3001x; 1.0473x over previous
//
#include <hip/hip_runtime.h>

#define BS   64
#define NQ   3000
#define NC   256
#define FH   100
#define FW   100
#define TOPK 1500

// ---------------- Kernel A: scores[b,q] = max_c class[b,q,c] ----------------
// One row (64 float4) per wave-iteration; 4 rows per wave for 4 outstanding
// loads. Lane l reads float4 l of each row (1 KB coalesced per instruction).
// Memory-bound at ~31 us floor (196.6 MB @ 6.3 TB/s) — at roofline.
__global__ __launch_bounds__(256) void scores_kernel(const float4* __restrict__ cls,
                                                     float* __restrict__ scores) {
    const int tid  = threadIdx.x;
    const int lane = tid & 63;
    const int wave = tid >> 6;
    const int row0 = blockIdx.x * 16 + wave * 4;  // 16 rows per block, grid exact
    const float4* p = cls + (size_t)row0 * (NC / 4) + lane;
    float4 a = p[0], b = p[64], c = p[128], d = p[192];
    float m0 = fmaxf(fmaxf(a.x, a.y), fmaxf(a.z, a.w));
    float m1 = fmaxf(fmaxf(b.x, b.y), fmaxf(b.z, b.w));
    float m2 = fmaxf(fmaxf(c.x, c.y), fmaxf(c.z, c.w));
    float m3 = fmaxf(fmaxf(d.x, d.y), fmaxf(d.z, d.w));
#pragma unroll
    for (int off = 32; off > 0; off >>= 1) {
        m0 = fmaxf(m0, __shfl_xor(m0, off, 64));
        m1 = fmaxf(m1, __shfl_xor(m1, off, 64));
        m2 = fmaxf(m2, __shfl_xor(m2, off, 64));
        m3 = fmaxf(m3, __shfl_xor(m3, off, 64));
    }
    if (lane < 4) {
        float m = (lane == 0) ? m0 : (lane == 1) ? m1 : (lane == 2) ? m2 : m3;
        scores[row0 + lane] = m;
    }
}

// -------- Kernel B: select + stripe-raster + direct emit (2-kernel chain) ----
// Row-stripe decomposition: grid (NSTRIPE, BS); block (part,b) owns output
// rows [part*13, part*13+13) of batch b. Every block redundantly computes the
// per-batch threshold (radix descent; redundancy runs in parallel on
// otherwise-idle CUs = free) and the scalar tie cutoff, then rasterizes ALL
// selected boxes CLIPPED TO ITS STRIPE via scatter LDS atomicOr (proven in
// R1; R3's gather loop was slower), and writes its rows of the FINAL float
// mask directly. Blocks are fully independent: no partial planes, no
// reduction kernel, no device-scope fences (R2 lesson: fences cost 170us).
#define NSTRIPE 8
#define RPS     13   // rows per stripe: 8*13 = 104 >= 100
#define NTM     512  // 8 waves

__global__ __launch_bounds__(NTM) void raster_kernel(const float4* __restrict__ coord,
                                                     const int* __restrict__ vfs,
                                                     const float* __restrict__ scores,
                                                     float* __restrict__ out) {
    __shared__ __align__(16) unsigned su[NQ];  // score bits (positive: uint order == float order)
    __shared__ int      hist[8][256];   // per-wave histograms
    __shared__ int      eqlist[NQ];     // 24-bit-prefix candidates from pass 3
    __shared__ unsigned cov[RPS * 4];   // stripe coverage bitmap (52 words)
    __shared__ int      wave_sum[4];
    __shared__ int      s_selbin, s_K, s_c24, s_qcut;

    const int part = blockIdx.x;        // stripe within batch
    const int b    = blockIdx.y;        // batch
    const int tid  = threadIdx.x;
    const int wid  = tid >> 6;
    const int r0   = part * RPS;
    const int r1   = (r0 + RPS < FH) ? (r0 + RPS) : FH;

    // vectorized score load: NQ*4B = 12000B, 16B-aligned, 750 uint4
    {
        const uint4* sp = (const uint4*)(scores + b * NQ);
        uint4* sd = (uint4*)su;
        for (int i = tid; i < NQ / 4; i += NTM) sd[i] = sp[i];
    }
    if (tid < RPS * 4) cov[tid] = 0u;
    if (tid == 0) s_c24 = 0;

    // ---- byte-wise radix descent with parallel suffix-scan bin select ----
    // Tie candidates (24-bit prefix matches) are collected during pass 3,
    // eliminating a separate full-NQ scan (logic proven correct in R2).
    unsigned prefix = 0, pmask = 0;
    int K = TOPK;
#pragma unroll
    for (int p = 0; p < 4; ++p) {
        const int shift = 24 - 8 * p;
        for (int i = tid; i < 8 * 256; i += NTM) ((int*)hist)[i] = 0;
        __syncthreads();
        for (int q = tid; q < NQ; q += NTM) {
            unsigned u = su[q];
            if ((u & pmask) == prefix) {
                if (p == 3) eqlist[atomicAdd(&s_c24, 1)] = q;
                atomicAdd(&hist[wid][(u >> shift) & 0xFF], 1);
            }
        }
        __syncthreads();
        // first 256 threads: suffix scan over bins (reversed index = prefix scan)
        int x = 0, hx = 0, bin = 0;
        if (tid < 256) {
            bin = 255 - tid;
            hx = hist[0][bin] + hist[1][bin] + hist[2][bin] + hist[3][bin] +
                 hist[4][bin] + hist[5][bin] + hist[6][bin] + hist[7][bin];
            x = hx;
#pragma unroll
            for (int off = 1; off < 64; off <<= 1) {
                int y = __shfl_up(x, off, 64);
                if ((tid & 63) >= off) x += y;
            }
            if ((tid & 63) == 63) wave_sum[tid >> 6] = x;
        }
        __syncthreads();
        if (tid < 256) {
            int w = tid >> 6;
            for (int j = 0; j < w; ++j) x += wave_sum[j];
            int ge_incl = x;          // count of prefix-matching su with byte >= bin
            int ge_excl = x - hx;     // count with byte > bin
            if (ge_incl >= K && ge_excl < K) {
                s_selbin = bin;
                s_K      = K - ge_excl;
            }
        }
        __syncthreads();
        prefix |= ((unsigned)s_selbin) << shift;
        pmask  |= (0xFFu << shift);
        K = s_K;
        __syncthreads();
    }
    const unsigned v      = prefix;  // exact bits of TOPK-th largest
    const int      e_take = K;       // how many su==v to take (smallest indices)

    // ---- tie cutoff from pass-3 candidates: tie q selected iff q < qcut ----
    const int C24 = s_c24;           // 24-bit-prefix matches (small in practice)
    for (int i = tid; i < C24; i += NTM) {
        int q = eqlist[i];
        if (su[q] == v) {
            int r = 0;
            for (int j = 0; j < C24; ++j) {
                int qj = eqlist[j];
                r += (su[qj] == v && qj < q) ? 1 : 0;
            }
            if (r == e_take - 1) s_qcut = q + 1;  // unique writer (indices distinct)
        }
    }
    __syncthreads();
    const int qcut = s_qcut;

    const float s0 = (float)vfs[2 * b];      // reference scales x by vfs[:,0]
    const float s1 = (float)vfs[2 * b + 1];  // and y by vfs[:,1] (quirk replicated)

    // ---- selection + scatter-raster of ALL queries, clipped to stripe ----
    for (int q = tid; q < NQ; q += NTM) {
        unsigned u = su[q];
        if (u > v || (u == v && q < qcut)) {
            float4 c4 = coord[(size_t)b * NQ + q];
            float x1 = c4.x - 0.5f * c4.z, y1 = c4.y - 0.5f * c4.w;
            float x2 = c4.x + 0.5f * c4.z, y2 = c4.y + 0.5f * c4.w;
            int lx = (int)floorf(x1 * s0), ly = (int)floorf(y1 * s1);
            int rx = (int)floorf(x2 * s0), ry = (int)floorf(y2 * s1);
            int h0 = ly > r0 ? ly : r0, h1 = ry < r1 ? ry : r1;   // stripe clip
            int w0 = lx > 0 ? lx : 0,   w1 = rx < FW ? rx : FW;
            if (h0 < h1 && w0 < w1) {
                unsigned m[4];
#pragma unroll
                for (int j = 0; j < 4; ++j) {
                    int lo = w0 - 32 * j; lo = lo < 0 ? 0 : lo;
                    int hi = w1 - 32 * j; hi = hi > 32 ? 32 : hi;
                    unsigned mm = 0u;
                    if (hi > lo) {
                        unsigned top = (hi >= 32) ? 0xFFFFFFFFu : ((1u << hi) - 1u);
                        unsigned bot = (lo <= 0) ? 0u : ((1u << lo) - 1u);
                        mm = top & ~bot;
                    }
                    m[j] = mm;
                }
                for (int h = h0; h < h1; ++h) {
#pragma unroll
                    for (int j = 0; j < 4; ++j)
                        if (m[j]) atomicOr(&cov[(h - r0) * 4 + j], m[j]);
                }
            }
        }
    }
    __syncthreads();

    // ---- fused emit: write final float mask rows [r0,r1), float4 stores ----
    const int iv0 = vfs[2 * b], iv1 = vfs[2 * b + 1];
    const int nrow = r1 - r0;
    float4* out4 = (float4*)(out + (size_t)b * (FH * FW));
    for (int idx = tid; idx < nrow * (FW / 4); idx += NTM) {
        const int hr = idx / (FW / 4);
        const int w4 = idx - hr * (FW / 4);
        const int h  = r0 + hr;
        const int w  = w4 * 4;                      // w%32 in {0,4,...,28}: one word
        const unsigned word = cov[hr * 4 + (w >> 5)];
        const bool padr = (h >= iv0);
        float4 o;
        o.x = (((word >> ((w + 0) & 31)) & 1u) && !(padr || (w + 0 >= iv1))) ? 0.0f : -1e20f;
        o.y = (((word >> ((w + 1) & 31)) & 1u) && !(padr || (w + 1 >= iv1))) ? 0.0f : -1e20f;
        o.z = (((word >> ((w + 2) & 31)) & 1u) && !(padr || (w + 2 >= iv1))) ? 0.0f : -1e20f;
        o.w = (((word >> ((w + 3) & 31)) & 1u) && !(padr || (w + 3 >= iv1))) ? 0.0f : -1e20f;
        out4[h * (FW / 4) + w4] = o;
    }
}

extern "C" void kernel_launch(void* const* d_in, const int* in_sizes, int n_in,
                              void* d_out, int out_size, void* d_ws, size_t ws_size,
                              hipStream_t stream) {
    const float4* coord = (const float4*)d_in[0];  // (BS, NQ, 4) f32
    const float*  cls   = (const float*)d_in[1];   // (BS, NQ, NC) f32
    const int*    vfs   = (const int*)d_in[2];     // (BS, 2) i32
    // d_in[3] (padding_mask) ignored — recomputed from vfs.
    float* scores = (float*)d_ws;                  // BS*NQ f32 = 768000 B
    float* out    = (float*)d_out;

    const int rows = BS * NQ;  // 192000
    scores_kernel<<<rows / 16, 256, 0, stream>>>((const float4*)cls, scores);
    raster_kernel<<<dim3(NSTRIPE, BS), NTM, 0, stream>>>(coord, vfs, scores, out);
}

// Round 5
// 297.752 us; speedup vs baseline: 1.3494x; 1.0379x over previous
//
#include <hip/hip_runtime.h>

#define BS   64
#define NQ   3000
#define NC   256
#define FH   100
#define FW   100
#define TOPK 1500

// ---------------- Kernel A: scores[b,q] = max_c class[b,q,c] ----------------
// One row (64 float4) per wave-iteration; 4 rows per wave for 4 outstanding
// loads. Lane l reads float4 l of each row (1 KB coalesced per instruction).
// Memory-bound at ~31 us floor (196.6 MB @ 6.3 TB/s) — at roofline.
__global__ __launch_bounds__(256) void scores_kernel(const float4* __restrict__ cls,
                                                     float* __restrict__ scores) {
    const int tid  = threadIdx.x;
    const int lane = tid & 63;
    const int wave = tid >> 6;
    const int row0 = blockIdx.x * 16 + wave * 4;  // 16 rows per block, grid exact
    const float4* p = cls + (size_t)row0 * (NC / 4) + lane;
    float4 a = p[0], b = p[64], c = p[128], d = p[192];
    float m0 = fmaxf(fmaxf(a.x, a.y), fmaxf(a.z, a.w));
    float m1 = fmaxf(fmaxf(b.x, b.y), fmaxf(b.z, b.w));
    float m2 = fmaxf(fmaxf(c.x, c.y), fmaxf(c.z, c.w));
    float m3 = fmaxf(fmaxf(d.x, d.y), fmaxf(d.z, d.w));
#pragma unroll
    for (int off = 32; off > 0; off >>= 1) {
        m0 = fmaxf(m0, __shfl_xor(m0, off, 64));
        m1 = fmaxf(m1, __shfl_xor(m1, off, 64));
        m2 = fmaxf(m2, __shfl_xor(m2, off, 64));
        m3 = fmaxf(m3, __shfl_xor(m3, off, 64));
    }
    if (lane < 4) {
        float m = (lane == 0) ? m0 : (lane == 1) ? m1 : (lane == 2) ? m2 : m3;
        scores[row0 + lane] = m;
    }
}

// ---------------- Kernel B: per-(batch,slice) select + raster ----------------
// R1 structure (best measured: 301.3us) — grid (NSPLIT, BS) = 512 blocks.
// Every block redundantly computes the per-batch threshold (radix descent;
// redundancy runs in parallel on otherwise-idle CUs = free) + scalar tie
// cutoff, then scatter-rasters ONLY its NQ/NSPLIT query slice (~190 boxes,
// no duplicated box setup — R4's stripe variant duplicated it 8x and lost)
// into a private LDS bitmap -> partial plane. Scatter atomicOr beats the
// R3 gather loop (serial 190-iter dependent LDS reads lost ~20us).
// Micro-opts vs R1: tie candidates collected during radix pass 3 (deletes
// one full-NQ scan; proven R2/R4), float4 emit in kernel C.
#define NSPLIT 8
#define NTM    512  // 8 waves
#define QSLICE ((NQ + NSPLIT - 1) / NSPLIT)  // 375

__global__ __launch_bounds__(NTM) void raster_kernel(const float4* __restrict__ coord,
                                                     const int* __restrict__ vfs,
                                                     const float* __restrict__ scores,
                                                     unsigned* __restrict__ pcov) {
    __shared__ __align__(16) unsigned su[NQ];  // score bits (positive: uint order == float order)
    __shared__ int      hist[8][256];   // per-wave histograms
    __shared__ unsigned cov[FH * 4];    // 100 rows x 128-bit coverage (this slice)
    __shared__ int      eqlist[NQ];     // 24-bit-prefix candidates from pass 3
    __shared__ int      wave_sum[4];
    __shared__ int      s_selbin, s_K, s_c24, s_qcut;

    const int part = blockIdx.x;       // slice within batch
    const int b    = blockIdx.y;       // batch
    const int tid  = threadIdx.x;
    const int wid  = tid >> 6;

    // vectorized score load: NQ*4B = 12000B, 16B-aligned, 750 uint4
    {
        const uint4* sp = (const uint4*)(scores + b * NQ);
        uint4* sd = (uint4*)su;
        for (int i = tid; i < NQ / 4; i += NTM) sd[i] = sp[i];
    }
    for (int i = tid; i < FH * 4; i += NTM) cov[i] = 0u;
    if (tid == 0) s_c24 = 0;

    // ---- byte-wise radix descent with parallel suffix-scan bin select ----
    unsigned prefix = 0, pmask = 0;
    int K = TOPK;
#pragma unroll
    for (int p = 0; p < 4; ++p) {
        const int shift = 24 - 8 * p;
        for (int i = tid; i < 8 * 256; i += NTM) ((int*)hist)[i] = 0;
        __syncthreads();
        for (int q = tid; q < NQ; q += NTM) {
            unsigned u = su[q];
            if ((u & pmask) == prefix) {
                if (p == 3) eqlist[atomicAdd(&s_c24, 1)] = q;
                atomicAdd(&hist[wid][(u >> shift) & 0xFF], 1);
            }
        }
        __syncthreads();
        // first 256 threads: suffix scan over bins (reversed index = prefix scan)
        int x = 0, hx = 0, bin = 0;
        if (tid < 256) {
            bin = 255 - tid;
            hx = hist[0][bin] + hist[1][bin] + hist[2][bin] + hist[3][bin] +
                 hist[4][bin] + hist[5][bin] + hist[6][bin] + hist[7][bin];
            x = hx;
#pragma unroll
            for (int off = 1; off < 64; off <<= 1) {
                int y = __shfl_up(x, off, 64);
                if ((tid & 63) >= off) x += y;
            }
            if ((tid & 63) == 63) wave_sum[tid >> 6] = x;
        }
        __syncthreads();
        if (tid < 256) {
            int w = tid >> 6;
            for (int j = 0; j < w; ++j) x += wave_sum[j];
            int ge_incl = x;          // count of prefix-matching su with byte >= bin
            int ge_excl = x - hx;     // count with byte > bin
            if (ge_incl >= K && ge_excl < K) {
                s_selbin = bin;
                s_K      = K - ge_excl;
            }
        }
        __syncthreads();
        prefix |= ((unsigned)s_selbin) << shift;
        pmask  |= (0xFFu << shift);
        K = s_K;
        __syncthreads();
    }
    const unsigned v      = prefix;  // exact bits of TOPK-th largest
    const int      e_take = K;       // how many su==v to take (smallest indices)

    // ---- tie cutoff from pass-3 candidates: tie q selected iff q < qcut ----
    const int C24 = s_c24;           // 24-bit-prefix matches (small in practice)
    for (int i = tid; i < C24; i += NTM) {
        int q = eqlist[i];
        if (su[q] == v) {
            int r = 0;
            for (int j = 0; j < C24; ++j) {
                int qj = eqlist[j];
                r += (su[qj] == v && qj < q) ? 1 : 0;
            }
            if (r == e_take - 1) s_qcut = q + 1;  // unique writer (indices distinct)
        }
    }
    __syncthreads();
    const int qcut = s_qcut;

    const float s0 = (float)vfs[2 * b];      // reference scales x by vfs[:,0]
    const float s1 = (float)vfs[2 * b + 1];  // and y by vfs[:,1] (quirk replicated)

    // ---- selection + scatter-raster of own slice (~190 boxes) -------------
    const int q0 = part * QSLICE;
    const int q1 = (q0 + QSLICE < NQ) ? (q0 + QSLICE) : NQ;
    for (int q = q0 + tid; q < q1; q += NTM) {
        unsigned u = su[q];
        if (u > v || (u == v && q < qcut)) {
            float4 c4 = coord[(size_t)b * NQ + q];
            float x1 = c4.x - 0.5f * c4.z, y1 = c4.y - 0.5f * c4.w;
            float x2 = c4.x + 0.5f * c4.z, y2 = c4.y + 0.5f * c4.w;
            int lx = (int)floorf(x1 * s0), ly = (int)floorf(y1 * s1);
            int rx = (int)floorf(x2 * s0), ry = (int)floorf(y2 * s1);
            int h0 = ly > 0 ? ly : 0, h1 = ry < FH ? ry : FH;
            int w0 = lx > 0 ? lx : 0, w1 = rx < FW ? rx : FW;
            if (h0 < h1 && w0 < w1) {
                unsigned m[4];
#pragma unroll
                for (int j = 0; j < 4; ++j) {
                    int lo = w0 - 32 * j; lo = lo < 0 ? 0 : lo;
                    int hi = w1 - 32 * j; hi = hi > 32 ? 32 : hi;
                    unsigned mm = 0u;
                    if (hi > lo) {
                        unsigned top = (hi >= 32) ? 0xFFFFFFFFu : ((1u << hi) - 1u);
                        unsigned bot = (lo <= 0) ? 0u : ((1u << lo) - 1u);
                        mm = top & ~bot;
                    }
                    m[j] = mm;
                }
                for (int h = h0; h < h1; ++h) {
#pragma unroll
                    for (int j = 0; j < 4; ++j)
                        if (m[j]) atomicOr(&cov[h * 4 + j], m[j]);
                }
            }
        }
    }
    __syncthreads();

    // ---- dump partial coverage plane ----
    unsigned* dst = pcov + (size_t)(b * NSPLIT + part) * (FH * 4);
    for (int i = tid; i < FH * 4; i += NTM) dst[i] = cov[i];
}

// ---------------- Kernel C: OR partials + fuse padding -> mask (float4) -----
__global__ __launch_bounds__(256) void emit_kernel(const unsigned* __restrict__ pcov,
                                                   const int* __restrict__ vfs,
                                                   float* __restrict__ out) {
    const int idx = blockIdx.x * 256 + threadIdx.x;  // one float4 (4 cells) each
    if (idx >= BS * FH * (FW / 4)) return;
    const int b   = idx / (FH * (FW / 4));
    const int rem = idx - b * (FH * (FW / 4));
    const int h   = rem / (FW / 4);
    const int w4  = rem - h * (FW / 4);
    const int w   = w4 * 4;  // 4-aligned, <100: all 4 bits in one 32-bit word
    const unsigned* p = pcov + (size_t)b * NSPLIT * (FH * 4) + h * 4 + (w >> 5);
    unsigned acc = 0u;
#pragma unroll
    for (int s = 0; s < NSPLIT; ++s) acc |= p[s * (FH * 4)];
    const int  iv0  = vfs[2 * b], iv1 = vfs[2 * b + 1];
    const bool padr = (h >= iv0);
    float4 o;
    o.x = (((acc >> ((w + 0) & 31)) & 1u) && !(padr || (w + 0 >= iv1))) ? 0.0f : -1e20f;
    o.y = (((acc >> ((w + 1) & 31)) & 1u) && !(padr || (w + 1 >= iv1))) ? 0.0f : -1e20f;
    o.z = (((acc >> ((w + 2) & 31)) & 1u) && !(padr || (w + 2 >= iv1))) ? 0.0f : -1e20f;
    o.w = (((acc >> ((w + 3) & 31)) & 1u) && !(padr || (w + 3 >= iv1))) ? 0.0f : -1e20f;
    ((float4*)out)[idx] = o;
}

extern "C" void kernel_launch(void* const* d_in, const int* in_sizes, int n_in,
                              void* d_out, int out_size, void* d_ws, size_t ws_size,
                              hipStream_t stream) {
    const float4* coord = (const float4*)d_in[0];  // (BS, NQ, 4) f32
    const float*  cls   = (const float*)d_in[1];   // (BS, NQ, NC) f32
    const int*    vfs   = (const int*)d_in[2];     // (BS, 2) i32
    // d_in[3] (padding_mask) ignored — recomputed from vfs.
    float*    scores = (float*)d_ws;                           // 768000 B
    unsigned* pcov   = (unsigned*)((char*)d_ws + (size_t)BS * NQ * sizeof(float));
                                                               // 819200 B
    float* out = (float*)d_out;

    const int rows = BS * NQ;  // 192000
    scores_kernel<<<rows / 16, 256, 0, stream>>>((const float4*)cls, scores);
    raster_kernel<<<dim3(NSPLIT, BS), NTM, 0, stream>>>(coord, vfs, scores, pcov);
    const int emit_elems = BS * FH * (FW / 4);     // 160000
    emit_kernel<<<(emit_elems + 255) / 256, 256, 0, stream>>>(pcov, vfs, out);
}